// Round 6
// baseline (3838.718 us; speedup 1.0000x reference)
//
#include <hip/hip_runtime.h>
#include <math.h>

// Problem constants (fixed by reference).
#define HIDDEN 1024
#define MEL    80
#define TSTEPS 1000
#define BATCH  64

// 64 persistent blocks x 1024 threads (16 waves). Block owns 16 hidden units
// = 64 gate rows (one full 64B mailbox line per producer -- R4: multi-writer
// lines are poison). Wave wv owns column slice [wv*64, wv*64+64); lane = gate
// row in MAC phase, lane = column (slot 64*wv+lane) in poll phase. A wave's
// MAC needs ONLY the 64 h values its own lanes poll -> no block barrier
// between poll and MAC; the single per-step __syncthreads (B) sits before
// wave0's reduction.
// R8 (kept): 4B packed {tag:8 | h:Q0.23}; quant err 2^-24 << 8.3e-4.
// R12 (kept): arrival-order chunked MAC (hides MAC under straggler wait).
// R13 (this round): UNCACHED rendezvous. R0-R5 are all within +/-3% -> step
// is dominated by one latency term: the probe-filter path (write-through
// store -> IC -> invalidate 8 sharer L2s -> consumer miss -> refill), since
// poll EA traffic (~13.5KB/step = 1 refill/line/XCD/step) proves polls are
// local-L2 hits. Fix: poll loads AND publish stores use `sc0 sc1 nt`
// (no-allocate, IC-direct) inline asm -> no L2 sharers -> no probes; store
// completes at IC; next IC-direct poll sees it. Diagnostic: FETCH_SIZE must
// balloon (every poll now reaches EA) else bypass didn't engage.
#define NBLK 64
#define TPB  1024

typedef unsigned long long ull;

// IC-direct (no-allocate) 4B load/store. `nt` = no L2 allocation; sc0 sc1 =
// widest scope intent. Aligned 4B is naturally atomic; tag travels with value
// in the same dword -> no fences needed.
__device__ __forceinline__ unsigned int ic_load(const unsigned int* p) {
    unsigned int v;
    asm volatile("global_load_dword %0, %1, off sc0 sc1 nt\n\ts_waitcnt vmcnt(0)"
                 : "=v"(v) : "v"(p) : "memory");
    return v;
}
__device__ __forceinline__ void ic_store(unsigned int* p, unsigned int v) {
    asm volatile("global_store_dword %0, %1, off sc0 sc1 nt"
                 :: "v"(p), "v"(v) : "memory");
}

// v_exp_f32-based activations (abs err ~1e-6 << 8.3e-4 threshold).
__device__ __forceinline__ float sigm_f(float x) { return 1.0f / (1.0f + __expf(-x)); }
__device__ __forceinline__ float tanh_f(float x) { return 1.0f - 2.0f / (1.0f + __expf(2.0f * x)); }

// {tag:8 | q:24}, q = rint(h * 2^23) clamped to +/-(2^23-1).
__device__ __forceinline__ unsigned int pack_h(float h, int tag) {
    int q = (int)rintf(h * 8388608.0f);          // 2^23
    q = max(-8388607, min(8388607, q));
    return ((unsigned int)(tag & 0xFF) << 24) | ((unsigned int)q & 0xFFFFFFu);
}
__device__ __forceinline__ float unpack_u(unsigned int v) {
    int q = ((int)(v << 8)) >> 8;                // sext24
    return (float)q * 1.1920928955078125e-7f;    // * 2^-23
}

__global__ __launch_bounds__(TPB, 4) void tts_recur(
    const float* __restrict__ dec_Wih,   // [4096, 80]
    const float* __restrict__ dec_Whh,   // [4096, 1024]
    const float* __restrict__ dec_bih,   // [4096]
    const float* __restrict__ dec_bhh,   // [4096]
    const float* __restrict__ lin_W,     // [80, 1024]
    const float* __restrict__ lin_b,     // [80]
    float* __restrict__ h_hist,          // [TSTEPS, 1024] (for epilogue)
    unsigned int* __restrict__ hbuf)     // [2, 1024] packed {tag:8|q:24}
{
    const int tid  = threadIdx.x;
    const int blk  = blockIdx.x;
    const int wv   = tid >> 6;           // 0..15: column slice / slot chunk
    const int lane = tid & 63;           // gate row (MAC) / column (poll)
    const int jj   = lane & 15;          // unit within block
    const int gate = lane >> 4;          // i,f,g,o
    const int unit_g = blk * 16 + jj;
    const int row_g  = gate * HIDDEN + unit_g;

    // Producer wave gets issue priority over the 15 spinning consumer waves.
    if (wv == 0) __builtin_amdgcn_s_setprio(3);

    __shared__ __align__(16) float hEx[16][64];   // per-wave h slice
    __shared__ float part[2][64 * 17];            // partials, pitch 17 (2-way = free)

    // ---- one-time fold: w = Whh_row_slice + Wih_row @ lin_W_slice (regs) ----
    const float* wih = dec_Wih + (size_t)row_g * MEL;
    const float* whh = dec_Whh + (size_t)row_g * HIDDEN + wv * 64;
    float4 w[16];
#pragma unroll
    for (int k = 0; k < 16; ++k)
        w[k] = *(const float4*)(whh + k * 4);
#pragma unroll 1
    for (int m = 0; m < MEL; ++m) {
        const float aw = wih[m];
        const float4* lw4 = (const float4*)(lin_W + (size_t)m * HIDDEN + wv * 64);
#pragma unroll
        for (int k = 0; k < 8; ++k) {
            const float4 lw = lw4[k];
            w[k].x = fmaf(aw, lw.x, w[k].x); w[k].y = fmaf(aw, lw.y, w[k].y);
            w[k].z = fmaf(aw, lw.z, w[k].z); w[k].w = fmaf(aw, lw.w, w[k].w);
        }
#pragma unroll
        for (int k = 8; k < 16; ++k) {
            const float4 lw = lw4[k];
            w[k].x = fmaf(aw, lw.x, w[k].x); w[k].y = fmaf(aw, lw.y, w[k].y);
            w[k].z = fmaf(aw, lw.z, w[k].z); w[k].w = fmaf(aw, lw.w, w[k].w);
        }
    }
    float b_comb_r = dec_bih[row_g] + dec_bhh[row_g];
    const float b_dec_r = b_comb_r;                  // step 0 (x=0, no lin_b fold)
    for (int m = 0; m < MEL; ++m)
        b_comb_r = fmaf(wih[m], lin_b[m], b_comb_r);

    float c_prev = 0.0f;                             // live on wave 0 lanes

    // ---- step 0: g = b_dec (h=c=x=0); wave 0 only ----
    if (wv == 0) {
        const float g = b_dec_r;
        const float gi = __shfl(g, jj, 64);
        const float gg = __shfl(g, 32 + jj, 64);
        const float go = __shfl(g, 48 + jj, 64);
        const float c  = sigm_f(gi) * tanh_f(gg);    // f-gate * c0 = 0
        const float h  = sigm_f(go) * tanh_f(c);
        c_prev = c;
        if (lane < 16) {
            ic_store(hbuf + unit_g, pack_h(h, 1));
            h_hist[unit_g] = h;
        }
    }

    // ---- steps 1..TSTEPS-1 ----
    for (int t = 1; t < TSTEPS; ++t) {
        const int buf = t & 1;
        // Arrival-order chunked poll+MAC. Lane IC-polls its own slot
        // (tag==t&0xFF; tag travels with value in one 4B word; 0xAA poison
        // never matches). When all 16 lanes of chunk c (= producer block
        // 4*wv+c's line) have arrived, MAC that chunk immediately.
        {
            const unsigned int* src = hbuf + ((t - 1) & 1) * HIDDEN + tid;
            const unsigned int want = (unsigned int)t & 0xFFu;
            bool mine = false;
            unsigned int pending = 0xFu;
            float cs0 = 0.f, cs1 = 0.f, cs2 = 0.f, cs3 = 0.f;
            const float4* hp = (const float4*)&hEx[wv][0];
            do {
                if (!mine) {
                    const unsigned int v = ic_load(src);
                    if ((v >> 24) == want) { hEx[wv][lane] = unpack_u(v); mine = true; }
                }
                // Fence: chunk ds_reads below must not be hoisted above the
                // ds_writes (per-wave DS ops execute in program order in HW;
                // wave_barrier stops compiler reordering).
                __builtin_amdgcn_wave_barrier();
                const ull rdy = __ballot(mine);
#pragma unroll
                for (int c = 0; c < 4; ++c) {
                    if ((pending >> c) & 1u) {
                        if (((rdy >> (16 * c)) & 0xFFFFull) == 0xFFFFull) {
                            const float4 h0 = hp[4*c], h1 = hp[4*c+1],
                                         h2 = hp[4*c+2], h3 = hp[4*c+3];
                            const float4 w0 = w[4*c], w1 = w[4*c+1],
                                         w2 = w[4*c+2], w3 = w[4*c+3];
                            float s0 = 0.f, s1 = 0.f;
                            s0 = fmaf(w0.x, h0.x, s0); s1 = fmaf(w0.y, h0.y, s1);
                            s0 = fmaf(w0.z, h0.z, s0); s1 = fmaf(w0.w, h0.w, s1);
                            s0 = fmaf(w1.x, h1.x, s0); s1 = fmaf(w1.y, h1.y, s1);
                            s0 = fmaf(w1.z, h1.z, s0); s1 = fmaf(w1.w, h1.w, s1);
                            s0 = fmaf(w2.x, h2.x, s0); s1 = fmaf(w2.y, h2.y, s1);
                            s0 = fmaf(w2.z, h2.z, s0); s1 = fmaf(w2.w, h2.w, s1);
                            s0 = fmaf(w3.x, h3.x, s0); s1 = fmaf(w3.y, h3.y, s1);
                            s0 = fmaf(w3.z, h3.z, s0); s1 = fmaf(w3.w, h3.w, s1);
                            const float cs = s0 + s1;
                            if (c == 0) cs0 = cs; else if (c == 1) cs1 = cs;
                            else if (c == 2) cs2 = cs; else cs3 = cs;
                            pending &= ~(1u << c);
                        }
                    }
                }
            } while (pending);
            part[buf][lane * 17 + wv] = (cs0 + cs1) + (cs2 + cs3);
        }
        __syncthreads();                               // barrier B (only one/step)

        if (wv == 0) {
            // Reduce 16 partials for this lane's row, then in-wave gates.
            const float* pr = &part[buf][lane * 17];
            float p[16];
#pragma unroll
            for (int i = 0; i < 16; ++i) p[i] = pr[i];
            const float s = (((p[0]+p[1])+(p[2]+p[3])) + ((p[4]+p[5])+(p[6]+p[7])))
                          + (((p[8]+p[9])+(p[10]+p[11])) + ((p[12]+p[13])+(p[14]+p[15])));
            const float g = s + b_comb_r;
            const float gi = __shfl(g, jj, 64);
            const float gf = __shfl(g, 16 + jj, 64);
            const float gg = __shfl(g, 32 + jj, 64);
            const float go = __shfl(g, 48 + jj, 64);
            const float c  = sigm_f(gf) * c_prev + sigm_f(gi) * tanh_f(gg);
            const float h  = sigm_f(go) * tanh_f(c);
            c_prev = c;
            if (lane < 16) {
                ic_store(hbuf + buf * HIDDEN + unit_g, pack_h(h, t + 1));
                h_hist[(size_t)t * HIDDEN + unit_g] = h;
            }
        }
        // Race-freedom: part is double-buffered across barrier B. hEx is
        // wave-private; chunk reads are ballot-gated after all 16 writes;
        // steps separated by barrier B. hbuf overwrite: h(t+1) overwrites
        // h(t-1) only after its producer observed ALL tags t+1 <- every block
        // published h(t) <- every block consumed h(t-1). Values+tags travel
        // atomically per 4B word. 8-bit tag: slot lag <=2 steps << 256.
        // R13: IC-direct loads always read the coherence point -> eventual
        // visibility is unconditional (no reliance on probe invalidations).
    }
}

// Epilogue: frame[t] = lin_W @ h[t] + lin_b, broadcast to 64 batch rows.
__global__ __launch_bounds__(128) void tts_frames(
    const float* __restrict__ lin_W, const float* __restrict__ lin_b,
    const float* __restrict__ h_hist, float* __restrict__ out)
{
    const int t = blockIdx.x;
    const int tid = threadIdx.x;
    __shared__ __align__(16) float h_sh[HIDDEN];
    __shared__ float f_s[MEL];
    const float4* src = (const float4*)(h_hist + (size_t)t * HIDDEN);
    ((float4*)h_sh)[tid] = src[tid];
    ((float4*)h_sh)[tid + 128] = src[tid + 128];
    __syncthreads();
    if (tid < MEL) {
        const float* wrow = lin_W + (size_t)tid * HIDDEN;
        float acc = lin_b[tid];
#pragma unroll 8
        for (int c = 0; c < HIDDEN; ++c)
            acc = fmaf(wrow[c], h_sh[c], acc);
        f_s[tid] = acc;
    }
    __syncthreads();
    for (int idx = tid; idx < BATCH * MEL; idx += 128) {
        const int b = idx / MEL;
        const int m = idx - b * MEL;
        out[(size_t)b * TSTEPS * MEL + (size_t)t * MEL + m] = f_s[m];
    }
}

extern "C" void kernel_launch(void* const* d_in, const int* in_sizes, int n_in,
                              void* d_out, int out_size, void* d_ws, size_t ws_size,
                              hipStream_t stream) {
    // Inputs: 0 text, 1 text_lens, 2 max_audio_len, 3 W_emb, 4..7 enc_*,
    // 8..11 dec_{Wih,Whh,bih,bhh}, 12 lin_W, 13 lin_b. Encoder is dead code.
    const float* dec_Wih = (const float*)d_in[8];
    const float* dec_Whh = (const float*)d_in[9];
    const float* dec_bih = (const float*)d_in[10];
    const float* dec_bhh = (const float*)d_in[11];
    const float* lin_W   = (const float*)d_in[12];
    const float* lin_b   = (const float*)d_in[13];
    float* out = (float*)d_out;

    // Workspace: h_hist fp32 [1000][1024] (4,096,000 B) + hbuf [2][1024] uint.
    // 0xAA poison -> tag byte 170 never matches the first polls -> no init pass.
    float* h_hist = (float*)d_ws;
    unsigned int* hbuf = (unsigned int*)((char*)d_ws + (size_t)TSTEPS * HIDDEN * sizeof(float));

    hipLaunchKernelGGL(tts_recur, dim3(NBLK), dim3(TPB), 0, stream,
                       dec_Wih, dec_Whh, dec_bih, dec_bhh, lin_W, lin_b, h_hist, hbuf);
    hipLaunchKernelGGL(tts_frames, dim3(TSTEPS), dim3(128), 0, stream,
                       lin_W, lin_b, h_hist, out);
}

// Round 7
// 3474.012 us; speedup vs baseline: 1.1050x; 1.1050x over previous
//
#include <hip/hip_runtime.h>
#include <math.h>

// Problem constants (fixed by reference).
#define HIDDEN 1024
#define MEL    80
#define TSTEPS 1000
#define BATCH  64

// R14: SINGLE-XCD RECURRENCE. R0-R6 established: cross-XCD rendezvous
// (publish -> IC -> probe-invalidate -> refill) costs ~1.3-1.5us/step and is
// insensitive to traffic (R1), scope (R2), poll cadence (R3/R6), and block
// spread (R4). The only structural escape is eliminating the cross-die path:
// place ALL worker blocks on ONE XCD so producer stores land in the SAME L2
// the consumers poll (store->load ~150-300ns). Weights fit one XCD contrary
// to the R0-session dismissal: per CU 512KB VGPR + 160KB LDS >= 512KB weight
// quota + working set at 8 waves/CU.
//   - 256 blocks launched (1/CU, LDS-bound); workers = blockIdx%8==0 -> the
//     round-robin blockIdx->XCD mapping puts all 32 workers on XCD 0.
//     CORRECT under any mapping (agent scope); placement is perf-only.
//   - Worker block: 512 thr (8 waves, 2/SIMD). Owns 32 units = 128 gate rows.
//     Lane (row=tid&127, cg=tid>>7) MACs 256 cols: 48 float4 in VGPR + 16
//     float4 in LDS ([chunk][tid] layout, 16B-stride = BW-floor only).
//   - Wave wv polls exactly the 256 h-slots its MAC needs (cg=wv>>1) -> no
//     block barrier between poll and MAC (R7 invariant). One __syncthreads
//     per step before the waves-0/1 reduce (4 partials/row) + gates.
// R8 (kept): 4B packed {tag:8|h:Q0.23}. R9 (kept): AGENT scope.
// R13 (reverted): nt/IC-direct polling (polls must stay L2-cached).
#define NBLK 256
#define TPB  512
#define UPB  32            // units per worker block
#define VREG 48            // float4 weight chunks in VGPR (cols 0..191)
#define LCH  16            // float4 weight chunks in LDS  (cols 192..255)

typedef unsigned long long ull;

// v_exp_f32-based activations (abs err ~1e-6 << 8.3e-4 threshold).
__device__ __forceinline__ float sigm_f(float x) { return 1.0f / (1.0f + __expf(-x)); }
__device__ __forceinline__ float tanh_f(float x) { return 1.0f - 2.0f / (1.0f + __expf(2.0f * x)); }

// {tag:8 | q:24}, q = rint(h * 2^23) clamped to +/-(2^23-1).
__device__ __forceinline__ unsigned int pack_h(float h, int tag) {
    int q = (int)rintf(h * 8388608.0f);          // 2^23
    q = max(-8388607, min(8388607, q));
    return ((unsigned int)(tag & 0xFF) << 24) | ((unsigned int)q & 0xFFFFFFu);
}
__device__ __forceinline__ float unpack_u(unsigned int v) {
    int q = ((int)(v << 8)) >> 8;                // sext24
    return (float)q * 1.1920928955078125e-7f;    // * 2^-23
}

__global__ __launch_bounds__(TPB, 2) void tts_recur(
    const float* __restrict__ dec_Wih,   // [4096, 80]
    const float* __restrict__ dec_Whh,   // [4096, 1024]
    const float* __restrict__ dec_bih,   // [4096]
    const float* __restrict__ dec_bhh,   // [4096]
    const float* __restrict__ lin_W,     // [80, 1024]
    const float* __restrict__ lin_b,     // [80]
    float* __restrict__ h_hist,          // [TSTEPS, 1024] (for epilogue)
    unsigned int* __restrict__ hbuf)     // [2, 1024] packed {tag:8|q:24}
{
    if (blockIdx.x & 7) return;          // non-worker (other XCDs): exit
    const int W    = blockIdx.x >> 3;    // worker id 0..31
    const int tid  = threadIdx.x;        // 0..511
    const int wv   = tid >> 6;           // wave 0..7
    const int lane = tid & 63;
    const int row  = tid & 127;          // local gate row (unit-major: j*4+gate)
    const int cg   = tid >> 7;           // column group 0..3 (256 cols each)
    const int unit0 = W * UPB;
    const int row_g = (row & 3) * HIDDEN + unit0 + (row >> 2);
    const int colbase = cg * 256;

    __shared__ __align__(16) float wlds[LCH * TPB * 4];  // 131072 B LDS weights
    __shared__ __align__(16) float hEx[8][256];          // 8 KB: per-wave h slice
                                                         // (fold reuses as lin_W row)
    __shared__ float part[2][128 * 5];                   // partials, pitch 5

    const float*  wih  = dec_Wih + (size_t)row_g * MEL;
    const float4* whh4 = (const float4*)(dec_Whh + (size_t)row_g * HIDDEN + colbase);
    float* lrow = (float*)hEx;                           // 1024-float staging

    // ---- fold pass L: LDS weight chunks (lane cols 192..255) ----
    // w = Whh_slice + Wih_row @ lin_W_slice. lin_W row staged through LDS
    // (uniform broadcast reads) to avoid a giant redundant L2 stream.
    {
        float4 t[LCH];
#pragma unroll
        for (int c = 0; c < LCH; ++c) t[c] = whh4[VREG + c];
#pragma unroll 1
        for (int m = 0; m < MEL; ++m) {
            __syncthreads();             // prior iter's readers done
            *(float2*)&lrow[tid * 2] = *(const float2*)(lin_W + (size_t)m * HIDDEN + tid * 2);
            __syncthreads();
            const float aw = wih[m];
            const float4* lw4 = (const float4*)&lrow[colbase];
#pragma unroll
            for (int c = 0; c < LCH; ++c) {
                const float4 lw = lw4[VREG + c];
                t[c].x = fmaf(aw, lw.x, t[c].x); t[c].y = fmaf(aw, lw.y, t[c].y);
                t[c].z = fmaf(aw, lw.z, t[c].z); t[c].w = fmaf(aw, lw.w, t[c].w);
            }
        }
#pragma unroll
        for (int c = 0; c < LCH; ++c)
            ((float4*)wlds)[c * TPB + tid] = t[c];
    }
    // ---- fold pass R: VGPR weight chunks (lane cols 0..191) ----
    float4 w[VREG];
#pragma unroll
    for (int k = 0; k < VREG; ++k) w[k] = whh4[k];
#pragma unroll 1
    for (int m = 0; m < MEL; ++m) {
        __syncthreads();
        *(float2*)&lrow[tid * 2] = *(const float2*)(lin_W + (size_t)m * HIDDEN + tid * 2);
        __syncthreads();
        const float aw = wih[m];
        const float4* lw4 = (const float4*)&lrow[colbase];
#pragma unroll
        for (int k = 0; k < VREG; ++k) {
            const float4 lw = lw4[k];
            w[k].x = fmaf(aw, lw.x, w[k].x); w[k].y = fmaf(aw, lw.y, w[k].y);
            w[k].z = fmaf(aw, lw.z, w[k].z); w[k].w = fmaf(aw, lw.w, w[k].w);
        }
    }
    __syncthreads();                     // lrow free; hEx now h-staging

    // ---- bias (reduce lanes only: tid<128, row==tid) ----
    float b_comb = 0.0f, b_dec = 0.0f, c_prev = 0.0f;
    if (tid < 128) {
        float b = dec_bih[row_g] + dec_bhh[row_g];
        b_dec = b;                       // step 0: x=0, no lin_b fold
        for (int m = 0; m < MEL; ++m)
            b = fmaf(wih[m], lin_b[m], b);
        b_comb = b;
    }

    // ---- step 0: g = b_dec (h=c=x=0) on waves 0,1 ----
    if (tid < 128) {
        const float g  = b_dec;
        const int   bl = lane & 60;      // base lane of this unit's 4-row group
        const float gi = __shfl(g, bl, 64);
        const float gg = __shfl(g, bl | 2, 64);
        const float go = __shfl(g, bl | 3, 64);
        const float c  = sigm_f(gi) * tanh_f(gg);    // f*c0 = 0
        const float h  = sigm_f(go) * tanh_f(c);
        c_prev = c;
        if ((lane & 3) == 0) {
            const int slot = unit0 + (row >> 2);
            __hip_atomic_store(hbuf + slot, pack_h(h, 1),
                               __ATOMIC_RELAXED, __HIP_MEMORY_SCOPE_AGENT);
            h_hist[slot] = h;
        }
    }

    // ---- steps 1..TSTEPS-1 ----
    for (int t = 1; t < TSTEPS; ++t) {
        const int buf = t & 1;
        // Poll: lane owns 4 consecutive slots (16B) of its wave's 256-col
        // group, read as 2x8B atomics (tag travels with value per 4B word;
        // 0xAA poison tag=170 never matches want=1,2). Same-XCD producer
        // store updates the shared L2 these polls hit.
        {
            const ull* src8 = (const ull*)(hbuf + ((t - 1) & 1) * HIDDEN)
                              + (cg * 128 + lane * 2);
            const unsigned int want = (unsigned int)t & 0xFFu;
            ull a  = __hip_atomic_load(src8,     __ATOMIC_RELAXED, __HIP_MEMORY_SCOPE_AGENT);
            ull b8 = __hip_atomic_load(src8 + 1, __ATOMIC_RELAXED, __HIP_MEMORY_SCOPE_AGENT);
            while ((((unsigned)(a  >> 24)) & 0xFFu) != want ||
                   ((unsigned)(a  >> 56))           != want ||
                   (((unsigned)(b8 >> 24)) & 0xFFu) != want ||
                   ((unsigned)(b8 >> 56))           != want) {
                a  = __hip_atomic_load(src8,     __ATOMIC_RELAXED, __HIP_MEMORY_SCOPE_AGENT);
                b8 = __hip_atomic_load(src8 + 1, __ATOMIC_RELAXED, __HIP_MEMORY_SCOPE_AGENT);
            }
            float4 hv;
            hv.x = unpack_u((unsigned)a);        hv.y = unpack_u((unsigned)(a >> 32));
            hv.z = unpack_u((unsigned)b8);       hv.w = unpack_u((unsigned)(b8 >> 32));
            *(float4*)&hEx[wv][lane * 4] = hv;   // wave-private slice
        }
        // Per-wave DS ops are program-ordered in HW; wave_barrier stops
        // compiler reordering of the uniform reads below above the writes.
        __builtin_amdgcn_wave_barrier();

        // MAC: 64 uniform ds_read_b128 (broadcast) + 16 private LDS-weight
        // reads + 256 FMAs into 4 accumulators. No block barrier (R7).
        const float4* hp = (const float4*)&hEx[wv][0];
        const float4* wl = (const float4*)wlds;
        float a0 = 0.f, a1 = 0.f, a2 = 0.f, a3 = 0.f;
#pragma unroll
        for (int k = 0; k < VREG; k += 4) {
            const float4 h0 = hp[k], h1 = hp[k+1], h2 = hp[k+2], h3 = hp[k+3];
            a0 = fmaf(w[k].x, h0.x, a0);   a0 = fmaf(w[k].y, h0.y, a0);
            a0 = fmaf(w[k].z, h0.z, a0);   a0 = fmaf(w[k].w, h0.w, a0);
            a1 = fmaf(w[k+1].x, h1.x, a1); a1 = fmaf(w[k+1].y, h1.y, a1);
            a1 = fmaf(w[k+1].z, h1.z, a1); a1 = fmaf(w[k+1].w, h1.w, a1);
            a2 = fmaf(w[k+2].x, h2.x, a2); a2 = fmaf(w[k+2].y, h2.y, a2);
            a2 = fmaf(w[k+2].z, h2.z, a2); a2 = fmaf(w[k+2].w, h2.w, a2);
            a3 = fmaf(w[k+3].x, h3.x, a3); a3 = fmaf(w[k+3].y, h3.y, a3);
            a3 = fmaf(w[k+3].z, h3.z, a3); a3 = fmaf(w[k+3].w, h3.w, a3);
        }
#pragma unroll
        for (int c = 0; c < LCH; c += 4) {
            const float4 h0 = hp[VREG+c], h1 = hp[VREG+c+1],
                         h2 = hp[VREG+c+2], h3 = hp[VREG+c+3];
            const float4 u0 = wl[c*TPB + tid],     u1 = wl[(c+1)*TPB + tid],
                         u2 = wl[(c+2)*TPB + tid], u3 = wl[(c+3)*TPB + tid];
            a0 = fmaf(u0.x, h0.x, a0); a0 = fmaf(u0.y, h0.y, a0);
            a0 = fmaf(u0.z, h0.z, a0); a0 = fmaf(u0.w, h0.w, a0);
            a1 = fmaf(u1.x, h1.x, a1); a1 = fmaf(u1.y, h1.y, a1);
            a1 = fmaf(u1.z, h1.z, a1); a1 = fmaf(u1.w, h1.w, a1);
            a2 = fmaf(u2.x, h2.x, a2); a2 = fmaf(u2.y, h2.y, a2);
            a2 = fmaf(u2.z, h2.z, a2); a2 = fmaf(u2.w, h2.w, a2);
            a3 = fmaf(u3.x, h3.x, a3); a3 = fmaf(u3.y, h3.y, a3);
            a3 = fmaf(u3.z, h3.z, a3); a3 = fmaf(u3.w, h3.w, a3);
        }
        part[buf][row * 5 + cg] = (a0 + a1) + (a2 + a3);
        __syncthreads();                               // barrier B (one/step)

        if (tid < 128) {
            // Reduce 4 partials for local row==tid, then in-wave gates.
            const float* pr = &part[buf][row * 5];
            const float g  = ((pr[0] + pr[1]) + (pr[2] + pr[3])) + b_comb;
            const int   bl = lane & 60;
            const float gi = __shfl(g, bl, 64);
            const float gf = __shfl(g, bl | 1, 64);
            const float gg = __shfl(g, bl | 2, 64);
            const float go = __shfl(g, bl | 3, 64);
            const float c  = sigm_f(gf) * c_prev + sigm_f(gi) * tanh_f(gg);
            const float h  = sigm_f(go) * tanh_f(c);
            c_prev = c;
            if ((lane & 3) == 0) {
                const int slot = unit0 + (row >> 2);
                __hip_atomic_store(hbuf + buf * HIDDEN + slot, pack_h(h, t + 1),
                                   __ATOMIC_RELAXED, __HIP_MEMORY_SCOPE_AGENT);
                h_hist[(size_t)t * HIDDEN + slot] = h;
            }
        }
        // Race-freedom (same proof as before, NBLK-independent): part is
        // double-buffered across barrier B; hEx slices wave-private with
        // program-order write-after-read; hbuf h(t+1) overwrites h(t-1) only
        // after its producer observed ALL tags t+1 <- every block published
        // h(t) <- every block consumed h(t-1). Values+tags atomic per 4B
        // word. 8-bit tag: slot lag <=2 steps << 256.
    }
}

// Epilogue: frame[t] = lin_W @ h[t] + lin_b, broadcast to 64 batch rows.
__global__ __launch_bounds__(128) void tts_frames(
    const float* __restrict__ lin_W, const float* __restrict__ lin_b,
    const float* __restrict__ h_hist, float* __restrict__ out)
{
    const int t = blockIdx.x;
    const int tid = threadIdx.x;
    __shared__ __align__(16) float h_sh[HIDDEN];
    __shared__ float f_s[MEL];
    const float4* src = (const float4*)(h_hist + (size_t)t * HIDDEN);
    ((float4*)h_sh)[tid] = src[tid];
    ((float4*)h_sh)[tid + 128] = src[tid + 128];
    __syncthreads();
    if (tid < MEL) {
        const float* wrow = lin_W + (size_t)tid * HIDDEN;
        float acc = lin_b[tid];
#pragma unroll 8
        for (int c = 0; c < HIDDEN; ++c)
            acc = fmaf(wrow[c], h_sh[c], acc);
        f_s[tid] = acc;
    }
    __syncthreads();
    for (int idx = tid; idx < BATCH * MEL; idx += 128) {
        const int b = idx / MEL;
        const int m = idx - b * MEL;
        out[(size_t)b * TSTEPS * MEL + (size_t)t * MEL + m] = f_s[m];
    }
}

extern "C" void kernel_launch(void* const* d_in, const int* in_sizes, int n_in,
                              void* d_out, int out_size, void* d_ws, size_t ws_size,
                              hipStream_t stream) {
    // Inputs: 0 text, 1 text_lens, 2 max_audio_len, 3 W_emb, 4..7 enc_*,
    // 8..11 dec_{Wih,Whh,bih,bhh}, 12 lin_W, 13 lin_b. Encoder is dead code.
    const float* dec_Wih = (const float*)d_in[8];
    const float* dec_Whh = (const float*)d_in[9];
    const float* dec_bih = (const float*)d_in[10];
    const float* dec_bhh = (const float*)d_in[11];
    const float* lin_W   = (const float*)d_in[12];
    const float* lin_b   = (const float*)d_in[13];
    float* out = (float*)d_out;

    // Workspace: h_hist fp32 [1000][1024] (4,096,000 B) + hbuf [2][1024] uint.
    // 0xAA poison -> tag byte 170 never matches the first polls -> no init pass.
    float* h_hist = (float*)d_ws;
    unsigned int* hbuf = (unsigned int*)((char*)d_ws + (size_t)TSTEPS * HIDDEN * sizeof(float));

    hipLaunchKernelGGL(tts_recur, dim3(NBLK), dim3(TPB), 0, stream,
                       dec_Wih, dec_Whh, dec_bih, dec_bhh, lin_W, lin_b, h_hist, hbuf);
    hipLaunchKernelGGL(tts_frames, dim3(TSTEPS), dim3(128), 0, stream,
                       lin_W, lin_b, h_hist, out);
}

// Round 8
// 3349.999 us; speedup vs baseline: 1.1459x; 1.0370x over previous
//
#include <hip/hip_runtime.h>
#include <math.h>

// Problem constants (fixed by reference).
#define HIDDEN 1024
#define MEL    80
#define TSTEPS 1000
#define BATCH  64

// R14/R15: SINGLE-XCD RECURRENCE, v2. R0-R6: cross-XCD rendezvous costs
// ~1.3-1.5us/step, insensitive to traffic/scope/poll tricks. R7 proved
// placement works (FETCH 37->15MB: weights once + L2-local mailbox) but was
// DS-pipe-bound: 640 ds_read_b128/CU/step ~= 3.2us ~= observed. v2 removes
// the LDS h-broadcast entirely: each wave's 64 lanes poll 4 cols each, so
// the wave's 256-col h slice is ALREADY in registers; broadcast via
// v_readlane (VALU->SGPR, not DS pipe; FMA takes 1 SGPR operand). MAC =
// 256 readlane + 256 FMA = 512 VALU/wave ~= 853ns/SIMD @2 waves; DS drops
// to 128 reads/CU (16 LDS weight chunks) ~= 640ns, overlapped.
//   - 256 blocks (1/CU, LDS-bound); workers blockIdx%8==0 -> 32 blocks on
//     XCD0 under round-robin mapping. Correct under ANY mapping (agent
//     scope); placement is perf-only.
//   - Worker: 512 thr (8 waves, 2/SIMD). Owns 32 units = 128 gate rows.
//     Lane: row=tid&127, wave's colgroup cg=tid>>7; 256 cols/lane via
//     48 float4 VGPR weights + 16 float4 LDS weights ([chunk][tid]).
//   - Poll: lane owns cols cg*256+4l..+3 (2x8B atomic loads, tag in each 4B
//     word); __all-gated exit -> every lane's hv valid before readlane MAC.
//     No LDS handoff for h -> no wave_barrier needed.
// R8 (kept): 4B packed {tag:8|h:Q0.23}. R9 (kept): AGENT scope.
#define NBLK 256
#define TPB  512
#define UPB  32            // units per worker block
#define VREG 48            // float4 weight chunks in VGPR (cols 0..191)
#define LCH  16            // float4 weight chunks in LDS  (cols 192..255)

typedef unsigned long long ull;

// v_exp_f32-based activations (abs err ~1e-6 << 8.3e-4 threshold).
__device__ __forceinline__ float sigm_f(float x) { return 1.0f / (1.0f + __expf(-x)); }
__device__ __forceinline__ float tanh_f(float x) { return 1.0f - 2.0f / (1.0f + __expf(2.0f * x)); }

// {tag:8 | q:24}, q = rint(h * 2^23) clamped to +/-(2^23-1).
__device__ __forceinline__ unsigned int pack_h(float h, int tag) {
    int q = (int)rintf(h * 8388608.0f);          // 2^23
    q = max(-8388607, min(8388607, q));
    return ((unsigned int)(tag & 0xFF) << 24) | ((unsigned int)q & 0xFFFFFFu);
}
__device__ __forceinline__ float unpack_u(unsigned int v) {
    int q = ((int)(v << 8)) >> 8;                // sext24
    return (float)q * 1.1920928955078125e-7f;    // * 2^-23
}

// Uniform broadcast of lane l's copy of v (VALU pipe, EXEC-ignoring).
__device__ __forceinline__ float rdlane(float v, int l) {
    return __int_as_float(__builtin_amdgcn_readlane(__float_as_int(v), l));
}

__global__ __launch_bounds__(TPB, 2) void tts_recur(
    const float* __restrict__ dec_Wih,   // [4096, 80]
    const float* __restrict__ dec_Whh,   // [4096, 1024]
    const float* __restrict__ dec_bih,   // [4096]
    const float* __restrict__ dec_bhh,   // [4096]
    const float* __restrict__ lin_W,     // [80, 1024]
    const float* __restrict__ lin_b,     // [80]
    float* __restrict__ h_hist,          // [TSTEPS, 1024] (for epilogue)
    unsigned int* __restrict__ hbuf)     // [2, 1024] packed {tag:8|q:24}
{
    if (blockIdx.x & 7) return;          // non-worker (other XCDs): exit
    const int W    = blockIdx.x >> 3;    // worker id 0..31
    const int tid  = threadIdx.x;        // 0..511
    const int lane = tid & 63;
    const int row  = tid & 127;          // local gate row (r&3=gate, r>>2=unit)
    const int cg   = tid >> 7;           // column group 0..3 (256 cols each)
    const int unit0 = W * UPB;
    const int row_g = (row & 3) * HIDDEN + unit0 + (row >> 2);
    const int colbase = cg * 256;

    __shared__ __align__(16) float wlds[LCH * TPB * 4];  // 131072 B LDS weights
    __shared__ __align__(16) float lrow[HIDDEN];         // fold staging (4 KB)
    __shared__ float part[2][128 * 5];                   // partials, pitch 5

    const float*  wih  = dec_Wih + (size_t)row_g * MEL;
    const float4* whh4 = (const float4*)(dec_Whh + (size_t)row_g * HIDDEN + colbase);

    // ---- fold pass L: LDS weight chunks (lane cols 192..255) ----
    // w = Whh_slice + Wih_row @ lin_W_slice; lin_W row staged through LDS.
    {
        float4 t[LCH];
#pragma unroll
        for (int c = 0; c < LCH; ++c) t[c] = whh4[VREG + c];
#pragma unroll 1
        for (int m = 0; m < MEL; ++m) {
            __syncthreads();             // prior iter's readers done
            *(float2*)&lrow[tid * 2] = *(const float2*)(lin_W + (size_t)m * HIDDEN + tid * 2);
            __syncthreads();
            const float aw = wih[m];
            const float4* lw4 = (const float4*)&lrow[colbase];
#pragma unroll
            for (int c = 0; c < LCH; ++c) {
                const float4 lw = lw4[VREG + c];
                t[c].x = fmaf(aw, lw.x, t[c].x); t[c].y = fmaf(aw, lw.y, t[c].y);
                t[c].z = fmaf(aw, lw.z, t[c].z); t[c].w = fmaf(aw, lw.w, t[c].w);
            }
        }
#pragma unroll
        for (int c = 0; c < LCH; ++c)
            ((float4*)wlds)[c * TPB + tid] = t[c];
    }
    // ---- fold pass R: VGPR weight chunks (lane cols 0..191) ----
    float4 w[VREG];
#pragma unroll
    for (int k = 0; k < VREG; ++k) w[k] = whh4[k];
#pragma unroll 1
    for (int m = 0; m < MEL; ++m) {
        __syncthreads();
        *(float2*)&lrow[tid * 2] = *(const float2*)(lin_W + (size_t)m * HIDDEN + tid * 2);
        __syncthreads();
        const float aw = wih[m];
        const float4* lw4 = (const float4*)&lrow[colbase];
#pragma unroll
        for (int k = 0; k < VREG; ++k) {
            const float4 lw = lw4[k];
            w[k].x = fmaf(aw, lw.x, w[k].x); w[k].y = fmaf(aw, lw.y, w[k].y);
            w[k].z = fmaf(aw, lw.z, w[k].z); w[k].w = fmaf(aw, lw.w, w[k].w);
        }
    }
    __syncthreads();

    // ---- bias (reduce lanes only: tid<128) ----
    float b_comb = 0.0f, b_dec = 0.0f, c_prev = 0.0f;
    if (tid < 128) {
        float b = dec_bih[row_g] + dec_bhh[row_g];
        b_dec = b;                       // step 0: x=0, no lin_b fold
        for (int m = 0; m < MEL; ++m)
            b = fmaf(wih[m], lin_b[m], b);
        b_comb = b;
    }

    // ---- step 0: g = b_dec (h=c=x=0) on waves 0,1 ----
    if (tid < 128) {
        const float g  = b_dec;
        const int   bl = lane & 60;      // base lane of this unit's 4-row group
        const float gi = __shfl(g, bl, 64);
        const float gg = __shfl(g, bl | 2, 64);
        const float go = __shfl(g, bl | 3, 64);
        const float c  = sigm_f(gi) * tanh_f(gg);    // f*c0 = 0
        const float h  = sigm_f(go) * tanh_f(c);
        c_prev = c;
        if ((lane & 3) == 0) {
            const int slot = unit0 + (row >> 2);
            __hip_atomic_store(hbuf + slot, pack_h(h, 1),
                               __ATOMIC_RELAXED, __HIP_MEMORY_SCOPE_AGENT);
            h_hist[slot] = h;
        }
    }

    // ---- steps 1..TSTEPS-1 ----
    for (int t = 1; t < TSTEPS; ++t) {
        const int buf = t & 1;
        // Poll: lane owns cols cg*256+4*lane..+3 as 2x8B atomics (tag rides
        // in each 4B word; 0xAA poison tag=170 never matches want=1,2).
        // __all-gated exit: every lane's hv valid before the readlane MAC.
        float4 hv;
        {
            const ull* src8 = (const ull*)(hbuf + ((t - 1) & 1) * HIDDEN)
                              + (cg * 128 + lane * 2);
            const unsigned int want = (unsigned int)t & 0xFFu;
            bool mine = false;
            do {
                if (!mine) {
                    const ull a  = __hip_atomic_load(src8,     __ATOMIC_RELAXED, __HIP_MEMORY_SCOPE_AGENT);
                    const ull b8 = __hip_atomic_load(src8 + 1, __ATOMIC_RELAXED, __HIP_MEMORY_SCOPE_AGENT);
                    if ((((unsigned)(a  >> 24)) & 0xFFu) == want &&
                        ((unsigned)(a  >> 56))           == want &&
                        (((unsigned)(b8 >> 24)) & 0xFFu) == want &&
                        ((unsigned)(b8 >> 56))           == want) {
                        hv.x = unpack_u((unsigned)a);   hv.y = unpack_u((unsigned)(a >> 32));
                        hv.z = unpack_u((unsigned)b8);  hv.w = unpack_u((unsigned)(b8 >> 32));
                        mine = true;
                    }
                }
            } while (!__all(mine));
        }

        // MAC: chunk k's 4 cols == lane k's hv. 256 readlane + 256 FMA, all
        // VALU; weights chunks 0..47 from VGPR, 48..63 from LDS (private
        // [chunk][tid] float4 reads, lane-consecutive = conflict-free).
        const float4* wl = (const float4*)wlds;
        float a0 = 0.f, a1 = 0.f, a2 = 0.f, a3 = 0.f;
#pragma unroll
        for (int k = 0; k < VREG; k += 4) {
            { const float4 ww = w[k];
              a0 = fmaf(ww.x, rdlane(hv.x, k), a0); a0 = fmaf(ww.y, rdlane(hv.y, k), a0);
              a0 = fmaf(ww.z, rdlane(hv.z, k), a0); a0 = fmaf(ww.w, rdlane(hv.w, k), a0); }
            { const float4 ww = w[k+1];
              a1 = fmaf(ww.x, rdlane(hv.x, k+1), a1); a1 = fmaf(ww.y, rdlane(hv.y, k+1), a1);
              a1 = fmaf(ww.z, rdlane(hv.z, k+1), a1); a1 = fmaf(ww.w, rdlane(hv.w, k+1), a1); }
            { const float4 ww = w[k+2];
              a2 = fmaf(ww.x, rdlane(hv.x, k+2), a2); a2 = fmaf(ww.y, rdlane(hv.y, k+2), a2);
              a2 = fmaf(ww.z, rdlane(hv.z, k+2), a2); a2 = fmaf(ww.w, rdlane(hv.w, k+2), a2); }
            { const float4 ww = w[k+3];
              a3 = fmaf(ww.x, rdlane(hv.x, k+3), a3); a3 = fmaf(ww.y, rdlane(hv.y, k+3), a3);
              a3 = fmaf(ww.z, rdlane(hv.z, k+3), a3); a3 = fmaf(ww.w, rdlane(hv.w, k+3), a3); }
        }
#pragma unroll
        for (int c = 0; c < LCH; c += 4) {
            const float4 u0 = wl[c*TPB + tid],     u1 = wl[(c+1)*TPB + tid],
                         u2 = wl[(c+2)*TPB + tid], u3 = wl[(c+3)*TPB + tid];
            const int s = VREG + c;      // src lanes 48..63
            a0 = fmaf(u0.x, rdlane(hv.x, s),   a0); a0 = fmaf(u0.y, rdlane(hv.y, s),   a0);
            a0 = fmaf(u0.z, rdlane(hv.z, s),   a0); a0 = fmaf(u0.w, rdlane(hv.w, s),   a0);
            a1 = fmaf(u1.x, rdlane(hv.x, s+1), a1); a1 = fmaf(u1.y, rdlane(hv.y, s+1), a1);
            a1 = fmaf(u1.z, rdlane(hv.z, s+1), a1); a1 = fmaf(u1.w, rdlane(hv.w, s+1), a1);
            a2 = fmaf(u2.x, rdlane(hv.x, s+2), a2); a2 = fmaf(u2.y, rdlane(hv.y, s+2), a2);
            a2 = fmaf(u2.z, rdlane(hv.z, s+2), a2); a2 = fmaf(u2.w, rdlane(hv.w, s+2), a2);
            a3 = fmaf(u3.x, rdlane(hv.x, s+3), a3); a3 = fmaf(u3.y, rdlane(hv.y, s+3), a3);
            a3 = fmaf(u3.z, rdlane(hv.z, s+3), a3); a3 = fmaf(u3.w, rdlane(hv.w, s+3), a3);
        }
        part[buf][row * 5 + cg] = (a0 + a1) + (a2 + a3);
        __syncthreads();                               // barrier B (one/step)

        if (tid < 128) {
            // Reduce 4 partials for local row==tid, then in-wave gates.
            const float* pr = &part[buf][row * 5];
            const float g  = ((pr[0] + pr[1]) + (pr[2] + pr[3])) + b_comb;
            const int   bl = lane & 60;
            const float gi = __shfl(g, bl, 64);
            const float gf = __shfl(g, bl | 1, 64);
            const float gg = __shfl(g, bl | 2, 64);
            const float go = __shfl(g, bl | 3, 64);
            const float c  = sigm_f(gf) * c_prev + sigm_f(gi) * tanh_f(gg);
            const float h  = sigm_f(go) * tanh_f(c);
            c_prev = c;
            if ((lane & 3) == 0) {
                const int slot = unit0 + (row >> 2);
                __hip_atomic_store(hbuf + buf * HIDDEN + slot, pack_h(h, t + 1),
                                   __ATOMIC_RELAXED, __HIP_MEMORY_SCOPE_AGENT);
                h_hist[(size_t)t * HIDDEN + slot] = h;
            }
        }
        // Race-freedom (same proof, NBLK-independent): part double-buffered
        // across barrier B; hv is register-private, __all-gated; readlane is
        // EXEC-ignoring but reads only post-poll values. hbuf h(t+1)
        // overwrites h(t-1) only after its producer observed ALL tags t+1 <-
        // every block published h(t) <- every block consumed h(t-1).
        // Values+tags atomic per 4B word. 8-bit tag: lag <=2 steps << 256.
    }
}

// Epilogue: frame[t] = lin_W @ h[t] + lin_b, broadcast to 64 batch rows.
__global__ __launch_bounds__(128) void tts_frames(
    const float* __restrict__ lin_W, const float* __restrict__ lin_b,
    const float* __restrict__ h_hist, float* __restrict__ out)
{
    const int t = blockIdx.x;
    const int tid = threadIdx.x;
    __shared__ __align__(16) float h_sh[HIDDEN];
    __shared__ float f_s[MEL];
    const float4* src = (const float4*)(h_hist + (size_t)t * HIDDEN);
    ((float4*)h_sh)[tid] = src[tid];
    ((float4*)h_sh)[tid + 128] = src[tid + 128];
    __syncthreads();
    if (tid < MEL) {
        const float* wrow = lin_W + (size_t)tid * HIDDEN;
        float acc = lin_b[tid];
#pragma unroll 8
        for (int c = 0; c < HIDDEN; ++c)
            acc = fmaf(wrow[c], h_sh[c], acc);
        f_s[tid] = acc;
    }
    __syncthreads();
    for (int idx = tid; idx < BATCH * MEL; idx += 128) {
        const int b = idx / MEL;
        const int m = idx - b * MEL;
        out[(size_t)b * TSTEPS * MEL + (size_t)t * MEL + m] = f_s[m];
    }
}

extern "C" void kernel_launch(void* const* d_in, const int* in_sizes, int n_in,
                              void* d_out, int out_size, void* d_ws, size_t ws_size,
                              hipStream_t stream) {
    // Inputs: 0 text, 1 text_lens, 2 max_audio_len, 3 W_emb, 4..7 enc_*,
    // 8..11 dec_{Wih,Whh,bih,bhh}, 12 lin_W, 13 lin_b. Encoder is dead code.
    const float* dec_Wih = (const float*)d_in[8];
    const float* dec_Whh = (const float*)d_in[9];
    const float* dec_bih = (const float*)d_in[10];
    const float* dec_bhh = (const float*)d_in[11];
    const float* lin_W   = (const float*)d_in[12];
    const float* lin_b   = (const float*)d_in[13];
    float* out = (float*)d_out;

    // Workspace: h_hist fp32 [1000][1024] (4,096,000 B) + hbuf [2][1024] uint.
    // 0xAA poison -> tag byte 170 never matches the first polls -> no init pass.
    float* h_hist = (float*)d_ws;
    unsigned int* hbuf = (unsigned int*)((char*)d_ws + (size_t)TSTEPS * HIDDEN * sizeof(float));

    hipLaunchKernelGGL(tts_recur, dim3(NBLK), dim3(TPB), 0, stream,
                       dec_Wih, dec_Whh, dec_bih, dec_bhh, lin_W, lin_b, h_hist, hbuf);
    hipLaunchKernelGGL(tts_frames, dim3(TSTEPS), dim3(128), 0, stream,
                       lin_W, lin_b, h_hist, out);
}

// Round 9
// 2158.888 us; speedup vs baseline: 1.7781x; 1.5517x over previous
//
#include <hip/hip_runtime.h>
#include <math.h>

// Problem constants (fixed by reference).
#define HIDDEN 1024
#define MEL    80
#define TSTEPS 1000
#define BATCH  64

// FINAL STRUCTURE (R5 revert, best of session): 64 persistent blocks x 1024
// threads (16 waves). Block owns 16 hidden units = 64 gate rows (one full
// 64B mailbox line per producer -- R4: multi-writer lines are poison).
// Wave wv owns column slice [wv*64, wv*64+64); lane = gate row in MAC phase,
// lane = column (slot 64*wv+lane) in poll phase. A wave's MAC needs ONLY the
// 64 h values its own lanes poll -> no block barrier between poll and MAC;
// the single per-step __syncthreads (B) sits before wave0's reduction.
//
// SESSION FLOOR EVIDENCE (R0-R8): step time ~2.07-2.18us is invariant under:
//   R1 traffic 1/2x (8B->4B mailbox): null. R2 scope SYSTEM->AGENT: null.
//   R3 4-deep staggered poll: null (same-address loads MSHR-merge).
//   R6 nt/IC-direct poll: -70% (IC RTT ~700-800ns SERIAL per poll).
//   R4 256-block spread: -45% (false sharing). R7/R8 single-XCD: -50%
//   (DS-pipe / readlane-VALU bound + unverifiable blockIdx->XCD placement).
// Decomposition: ~1.4us cross-XCD make-visible (publish -> IC/directory ->
// invalidate 8 sharer L2s -> consumer refill; polls are local-L2 hits per
// FETCH arithmetic: ~13.5KB/step = 1 refill/line/XCD) + ~0.6us serial local
// chain (wave0 reduce+gates ~0.3, detect ~0.2, barrier ~0.1). Escapes would
// require same-die compute with a non-VALU broadcast (scalar-path s_load) --
// untested; everything else measured null or negative.
//
// R8 (kept): 4B packed {tag:8|h:Q0.23}; quant err 2^-24 << 8.3e-4.
// R9 (kept): AGENT scope. R12 (kept): arrival-order chunked MAC -- each
// wave's 64 cols = 4 chunks of 16, chunk c == producer block 4*wv+c's line;
// __ballot-gated per-chunk MAC hides FMAs under straggler wait (VALUBusy
// 8.2->5.5%, best-in-band dur).
#define NBLK 64
#define TPB  1024

typedef unsigned long long ull;

// v_exp_f32-based activations (abs err ~1e-6 << 8.3e-4 threshold).
__device__ __forceinline__ float sigm_f(float x) { return 1.0f / (1.0f + __expf(-x)); }
__device__ __forceinline__ float tanh_f(float x) { return 1.0f - 2.0f / (1.0f + __expf(2.0f * x)); }

// {tag:8 | q:24}, q = rint(h * 2^23) clamped to +/-(2^23-1).
__device__ __forceinline__ unsigned int pack_h(float h, int tag) {
    int q = (int)rintf(h * 8388608.0f);          // 2^23
    q = max(-8388607, min(8388607, q));
    return ((unsigned int)(tag & 0xFF) << 24) | ((unsigned int)q & 0xFFFFFFu);
}
__device__ __forceinline__ float unpack_u(unsigned int v) {
    int q = ((int)(v << 8)) >> 8;                // sext24
    return (float)q * 1.1920928955078125e-7f;    // * 2^-23
}

__global__ __launch_bounds__(TPB, 4) void tts_recur(
    const float* __restrict__ dec_Wih,   // [4096, 80]
    const float* __restrict__ dec_Whh,   // [4096, 1024]
    const float* __restrict__ dec_bih,   // [4096]
    const float* __restrict__ dec_bhh,   // [4096]
    const float* __restrict__ lin_W,     // [80, 1024]
    const float* __restrict__ lin_b,     // [80]
    float* __restrict__ h_hist,          // [TSTEPS, 1024] (for epilogue)
    unsigned int* __restrict__ hbuf)     // [2, 1024] packed {tag:8|q:24}
{
    const int tid  = threadIdx.x;
    const int blk  = blockIdx.x;
    const int wv   = tid >> 6;           // 0..15: column slice / slot chunk
    const int lane = tid & 63;           // gate row (MAC) / column (poll)
    const int jj   = lane & 15;          // unit within block
    const int gate = lane >> 4;          // i,f,g,o
    const int unit_g = blk * 16 + jj;
    const int row_g  = gate * HIDDEN + unit_g;

    // Producer wave gets issue priority over the 15 spinning consumer waves.
    if (wv == 0) __builtin_amdgcn_s_setprio(3);

    __shared__ __align__(16) float hEx[16][64];   // per-wave h slice (single buffer:
                                                  // wave-private; chunk reads happen
                                                  // only after ballot-gated writes,
                                                  // steps separated by barrier B)
    __shared__ float part[2][64 * 17];            // partials, pitch 17 (2-way = free)

    // ---- one-time fold: w = Whh_row_slice + Wih_row @ lin_W_slice (regs) ----
    const float* wih = dec_Wih + (size_t)row_g * MEL;
    const float* whh = dec_Whh + (size_t)row_g * HIDDEN + wv * 64;
    float4 w[16];
#pragma unroll
    for (int k = 0; k < 16; ++k)
        w[k] = *(const float4*)(whh + k * 4);
#pragma unroll 1
    for (int m = 0; m < MEL; ++m) {
        const float aw = wih[m];
        const float4* lw4 = (const float4*)(lin_W + (size_t)m * HIDDEN + wv * 64);
#pragma unroll
        for (int k = 0; k < 8; ++k) {
            const float4 lw = lw4[k];
            w[k].x = fmaf(aw, lw.x, w[k].x); w[k].y = fmaf(aw, lw.y, w[k].y);
            w[k].z = fmaf(aw, lw.z, w[k].z); w[k].w = fmaf(aw, lw.w, w[k].w);
        }
#pragma unroll
        for (int k = 8; k < 16; ++k) {
            const float4 lw = lw4[k];
            w[k].x = fmaf(aw, lw.x, w[k].x); w[k].y = fmaf(aw, lw.y, w[k].y);
            w[k].z = fmaf(aw, lw.z, w[k].z); w[k].w = fmaf(aw, lw.w, w[k].w);
        }
    }
    float b_comb_r = dec_bih[row_g] + dec_bhh[row_g];
    const float b_dec_r = b_comb_r;                  // step 0 (x=0, no lin_b fold)
    for (int m = 0; m < MEL; ++m)
        b_comb_r = fmaf(wih[m], lin_b[m], b_comb_r);

    float c_prev = 0.0f;                             // live on wave 0 lanes

    // ---- step 0: g = b_dec (h=c=x=0); wave 0 only ----
    if (wv == 0) {
        const float g = b_dec_r;
        const float gi = __shfl(g, jj, 64);
        const float gg = __shfl(g, 32 + jj, 64);
        const float go = __shfl(g, 48 + jj, 64);
        const float c  = sigm_f(gi) * tanh_f(gg);    // f-gate * c0 = 0
        const float h  = sigm_f(go) * tanh_f(c);
        c_prev = c;
        if (lane < 16) {
            __hip_atomic_store(hbuf + unit_g, pack_h(h, 1),
                               __ATOMIC_RELAXED, __HIP_MEMORY_SCOPE_AGENT);
            h_hist[unit_g] = h;
        }
    }

    // ---- steps 1..TSTEPS-1 ----
    for (int t = 1; t < TSTEPS; ++t) {
        const int buf = t & 1;
        // Arrival-order chunked poll+MAC. Lane polls its own slot (tag==t&0xFF,
        // tag travels with the value in one 4B word -> no fences; 0xAA poison
        // never matches). When all 16 lanes of chunk c (= producer block
        // 4*wv+c's line) have arrived, MAC that chunk immediately.
        {
            const unsigned int* src = hbuf + ((t - 1) & 1) * HIDDEN + tid;
            const unsigned int want = (unsigned int)t & 0xFFu;
            bool mine = false;
            unsigned int pending = 0xFu;
            float cs0 = 0.f, cs1 = 0.f, cs2 = 0.f, cs3 = 0.f;
            const float4* hp = (const float4*)&hEx[wv][0];
            do {
                if (!mine) {
                    const unsigned int v = __hip_atomic_load(src, __ATOMIC_RELAXED,
                                                             __HIP_MEMORY_SCOPE_AGENT);
                    if ((v >> 24) == want) { hEx[wv][lane] = unpack_u(v); mine = true; }
                }
                // Fence: chunk ds_reads below must not be hoisted above the
                // ds_writes (per-wave DS ops execute in program order in HW;
                // wave_barrier stops compiler reordering).
                __builtin_amdgcn_wave_barrier();
                const ull rdy = __ballot(mine);
#pragma unroll
                for (int c = 0; c < 4; ++c) {
                    if ((pending >> c) & 1u) {
                        if (((rdy >> (16 * c)) & 0xFFFFull) == 0xFFFFull) {
                            const float4 h0 = hp[4*c], h1 = hp[4*c+1],
                                         h2 = hp[4*c+2], h3 = hp[4*c+3];
                            const float4 w0 = w[4*c], w1 = w[4*c+1],
                                         w2 = w[4*c+2], w3 = w[4*c+3];
                            float s0 = 0.f, s1 = 0.f;
                            s0 = fmaf(w0.x, h0.x, s0); s1 = fmaf(w0.y, h0.y, s1);
                            s0 = fmaf(w0.z, h0.z, s0); s1 = fmaf(w0.w, h0.w, s1);
                            s0 = fmaf(w1.x, h1.x, s0); s1 = fmaf(w1.y, h1.y, s1);
                            s0 = fmaf(w1.z, h1.z, s0); s1 = fmaf(w1.w, h1.w, s1);
                            s0 = fmaf(w2.x, h2.x, s0); s1 = fmaf(w2.y, h2.y, s1);
                            s0 = fmaf(w2.z, h2.z, s0); s1 = fmaf(w2.w, h2.w, s1);
                            s0 = fmaf(w3.x, h3.x, s0); s1 = fmaf(w3.y, h3.y, s1);
                            s0 = fmaf(w3.z, h3.z, s0); s1 = fmaf(w3.w, h3.w, s1);
                            const float cs = s0 + s1;
                            if (c == 0) cs0 = cs; else if (c == 1) cs1 = cs;
                            else if (c == 2) cs2 = cs; else cs3 = cs;
                            pending &= ~(1u << c);
                        }
                    }
                }
                // Disjointness: pending writers' slots belong to chunks that
                // have NOT fired; fired-chunk reads touch only arrived slots
                // whose lanes write no more this step. Deterministic combine:
            } while (pending);
            part[buf][lane * 17 + wv] = (cs0 + cs1) + (cs2 + cs3);
        }
        __syncthreads();                               // barrier B (only one/step)

        if (wv == 0) {
            // Reduce 16 partials for this lane's row, then in-wave gates.
            const float* pr = &part[buf][lane * 17];
            float p[16];
#pragma unroll
            for (int i = 0; i < 16; ++i) p[i] = pr[i];
            const float s = (((p[0]+p[1])+(p[2]+p[3])) + ((p[4]+p[5])+(p[6]+p[7])))
                          + (((p[8]+p[9])+(p[10]+p[11])) + ((p[12]+p[13])+(p[14]+p[15])));
            const float g = s + b_comb_r;
            const float gi = __shfl(g, jj, 64);
            const float gf = __shfl(g, 16 + jj, 64);
            const float gg = __shfl(g, 32 + jj, 64);
            const float go = __shfl(g, 48 + jj, 64);
            const float c  = sigm_f(gf) * c_prev + sigm_f(gi) * tanh_f(gg);
            const float h  = sigm_f(go) * tanh_f(c);
            c_prev = c;
            if (lane < 16) {
                __hip_atomic_store(hbuf + buf * HIDDEN + unit_g, pack_h(h, t + 1),
                                   __ATOMIC_RELAXED, __HIP_MEMORY_SCOPE_AGENT);
                h_hist[(size_t)t * HIDDEN + unit_g] = h;
            }
        }
        // Race-freedom: part is double-buffered across barrier B. hEx is
        // wave-private; within a step, chunk reads are ballot-gated after all
        // 16 writes; across steps, barrier B separates. hbuf overwrite:
        // h(t+1) overwrites h(t-1) only after its producer observed ALL tags
        // t+1 <- every block published h(t) <- every block consumed h(t-1).
        // 8-bit tag: slot lag <=2 steps << 256 -> no aliasing.
    }
}

// Epilogue: frame[t] = lin_W @ h[t] + lin_b, broadcast to 64 batch rows.
__global__ __launch_bounds__(128) void tts_frames(
    const float* __restrict__ lin_W, const float* __restrict__ lin_b,
    const float* __restrict__ h_hist, float* __restrict__ out)
{
    const int t = blockIdx.x;
    const int tid = threadIdx.x;
    __shared__ __align__(16) float h_sh[HIDDEN];
    __shared__ float f_s[MEL];
    const float4* src = (const float4*)(h_hist + (size_t)t * HIDDEN);
    ((float4*)h_sh)[tid] = src[tid];
    ((float4*)h_sh)[tid + 128] = src[tid + 128];
    __syncthreads();
    if (tid < MEL) {
        const float* wrow = lin_W + (size_t)tid * HIDDEN;
        float acc = lin_b[tid];
#pragma unroll 8
        for (int c = 0; c < HIDDEN; ++c)
            acc = fmaf(wrow[c], h_sh[c], acc);
        f_s[tid] = acc;
    }
    __syncthreads();
    for (int idx = tid; idx < BATCH * MEL; idx += 128) {
        const int b = idx / MEL;
        const int m = idx - b * MEL;
        out[(size_t)b * TSTEPS * MEL + (size_t)t * MEL + m] = f_s[m];
    }
}

extern "C" void kernel_launch(void* const* d_in, const int* in_sizes, int n_in,
                              void* d_out, int out_size, void* d_ws, size_t ws_size,
                              hipStream_t stream) {
    // Inputs: 0 text, 1 text_lens, 2 max_audio_len, 3 W_emb, 4..7 enc_*,
    // 8..11 dec_{Wih,Whh,bih,bhh}, 12 lin_W, 13 lin_b. Encoder is dead code.
    const float* dec_Wih = (const float*)d_in[8];
    const float* dec_Whh = (const float*)d_in[9];
    const float* dec_bih = (const float*)d_in[10];
    const float* dec_bhh = (const float*)d_in[11];
    const float* lin_W   = (const float*)d_in[12];
    const float* lin_b   = (const float*)d_in[13];
    float* out = (float*)d_out;

    // Workspace: h_hist fp32 [1000][1024] (4,096,000 B) + hbuf [2][1024] uint.
    // 0xAA poison -> tag byte 170 never matches the first polls -> no init pass.
    float* h_hist = (float*)d_ws;
    unsigned int* hbuf = (unsigned int*)((char*)d_ws + (size_t)TSTEPS * HIDDEN * sizeof(float));

    hipLaunchKernelGGL(tts_recur, dim3(NBLK), dim3(TPB), 0, stream,
                       dec_Wih, dec_Whh, dec_bih, dec_bhh, lin_W, lin_b, h_hist, hbuf);
    hipLaunchKernelGGL(tts_frames, dim3(TSTEPS), dim3(128), 0, stream,
                       lin_W, lin_b, h_hist, out);
}